// Round 2
// baseline (31.725 us; speedup 1.0000x reference)
//
#include <hip/hip_runtime.h>
#include <hip/hip_bf16.h>

// Stage 1+2: build zero-padded intermediate image inp_p[64][30][30] (fp32).
// inp_p[c][y][x] = inp[c][y-1][x-1] for interior, 0 on the 1-wide border.
// inp[c=2l+k][m][n] = sum_{jj in 0..1} sum_{i in 0..2} x[2l+jj][m][n+i-1] * w2[2l+jj][i][k]
__global__ void prep_kernel(const float* __restrict__ x,
                            const float* __restrict__ w2,
                            float* __restrict__ inp) {
    int idx = blockIdx.x * 256 + threadIdx.x;     // 0 .. 57599
    if (idx >= 64 * 30 * 30) return;
    int c   = idx / 900;
    int rem = idx % 900;
    int yp  = rem / 30;
    int xq  = rem % 30;
    float v = 0.f;
    if (yp >= 1 && yp <= 28 && xq >= 1 && xq <= 28) {
        int m = yp - 1, n = xq - 1;
        int l = c >> 1, k = c & 1;
        float acc = 0.f;
        for (int jj = 0; jj < 2; ++jj) {
            int j = l * 2 + jj;
            const float* xrow = x + (j * 28 + m) * 28;
            const float* w2p  = w2 + (j * 3) * 2 + k;   // w2[j][i][k], i stride 2
            for (int i = 0; i < 3; ++i) {
                int nn = n + i - 1;
                float xv = (nn >= 0 && nn < 28) ? xrow[nn] : 0.f;
                acc += xv * w2p[i * 2];
            }
        }
        v = acc;
    }
    inp[idx] = v;
}

// Stage 3: 3x3 conv, pad 1, Cin=64, Cout=128, 28x28 spatial.
// Block = 4 waves; each wave handles 16 input channels for the SAME outputs
// (o wave-uniform -> scalar weight loads), LDS reduction at the end.
// Lane covers output (row R = hg*4 + dh, cols w0, w0+1), 56 active lanes.
__global__ __launch_bounds__(256) void conv_kernel(const float* __restrict__ inp,
                                                   const float* __restrict__ w1,
                                                   float* __restrict__ y) {
    __shared__ float red[4][112];   // [wave][pixel*2 + comp]

    int b    = blockIdx.x;        // 0..895
    int o    = b / 7;             // wave-uniform output channel
    int hg   = b % 7;             // rows hg*4 .. hg*4+3
    int tid  = threadIdx.x;
    int wave = tid >> 6;          // 0..3 -> input-channel split
    int lane = tid & 63;
    int dh   = lane / 14;
    int wp   = lane % 14;
    bool active = (lane < 56);
    int dh2 = active ? dh : 0;    // keep reads in bounds for idle lanes
    int wp2 = active ? wp : 0;
    int R  = hg * 4 + dh2;        // output row
    int w0 = wp2 * 2;             // output cols w0, w0+1

    float acc0 = 0.f, acc1 = 0.f;
    const float* wbase = w1 + o * (32 * 3 * 3 * 2);   // w1[o][l][r][s][k]
    int cbase = wave * 16;

    #pragma unroll 4
    for (int cc = 0; cc < 16; ++cc) {
        int c = cbase + cc;
        const float* w9 = wbase + (c >> 1) * 18 + (c & 1);  // (r,s) at +(r*3+s)*2
        float w00 = w9[0],  w01 = w9[2],  w02 = w9[4];
        float w10 = w9[6],  w11 = w9[8],  w12 = w9[10];
        float w20 = w9[12], w21 = w9[14], w22 = w9[16];

        const float* ip = inp + c * 900 + R * 30 + w0;  // padded (R+dy, w0+dx)
        float2 a0 = *(const float2*)(ip + 0);
        float2 a1 = *(const float2*)(ip + 2);
        float2 b0 = *(const float2*)(ip + 30);
        float2 b1 = *(const float2*)(ip + 32);
        float2 c0 = *(const float2*)(ip + 60);
        float2 c1 = *(const float2*)(ip + 62);

        acc0 += a0.x * w00 + a0.y * w01 + a1.x * w02
              + b0.x * w10 + b0.y * w11 + b1.x * w12
              + c0.x * w20 + c0.y * w21 + c1.x * w22;
        acc1 += a0.y * w00 + a1.x * w01 + a1.y * w02
              + b0.y * w10 + b1.x * w11 + b1.y * w12
              + c0.y * w20 + c1.x * w21 + c1.y * w22;
    }

    if (active) {
        red[wave][lane * 2]     = acc0;
        red[wave][lane * 2 + 1] = acc1;
    }
    __syncthreads();

    if (tid < 112) {
        float s = red[0][tid] + red[1][tid] + red[2][tid] + red[3][tid];
        int pixel = tid >> 1;
        int comp  = tid & 1;
        int dh3 = pixel / 14;
        int wp3 = pixel % 14;
        int Ro  = hg * 4 + dh3;
        y[(o * 28 + Ro) * 28 + wp3 * 2 + comp] = s;
    }
}

extern "C" void kernel_launch(void* const* d_in, const int* in_sizes, int n_in,
                              void* d_out, int out_size, void* d_ws, size_t ws_size,
                              hipStream_t stream) {
    const float* x  = (const float*)d_in[0];   // (1,64,28,28) fp32
    const float* w1 = (const float*)d_in[1];   // (128,32,3,3,2) fp32
    const float* w2 = (const float*)d_in[2];   // (64,3,2) fp32
    float* yout = (float*)d_out;               // (1,128,28,28) fp32
    float* inp  = (float*)d_ws;                // padded [64][30][30] fp32 = 230400 B

    prep_kernel<<<dim3(225), dim3(256), 0, stream>>>(x, w2, inp);
    conv_kernel<<<dim3(896), dim3(256), 0, stream>>>(inp, w1, yout);
}

// Round 3
// 16.509 us; speedup vs baseline: 1.9217x; 1.9217x over previous
//
#include <hip/hip_runtime.h>
#include <hip/hip_bf16.h>

// One fused kernel. Block = (opair, band): output channels {2*opair, 2*opair+1},
// output rows band*4 .. band*4+3.
//
// Phase A: recompute stage1+2 (depthwise-W conv + pair-sum) for the 6 padded
//          rows this band needs, into LDS sA[c][pr][36] (px 0..29 valid,
//          30..35 pad for alignment). pr = padded row - band*4.
// Phase B: 3x3x64 conv. 224 active threads = 2 oo x 4 dh x 7 st x 4 c-split.
//          Each thread: 1x4 output strip, 16 interleaved channels.
//          Taps from LDS (float4+float2, 16B aligned), weights from global
//          (L1-resident, VMEM pipe). 4-way c-reduce through LDS.
__global__ __launch_bounds__(256) void fused_kernel(
    const float* __restrict__ x,    // [64][28][28]
    const float* __restrict__ w1,   // [128][32][3][3][2]
    const float* __restrict__ w2,   // [64][3][2]
    float* __restrict__ y)          // [128][28][28]
{
    __shared__ __align__(16) float sA[64 * 6 * 36];   // 55,296 B
    __shared__ __align__(16) float sRed[256][4];      //  4,096 B

    const int b     = blockIdx.x;     // 0..447
    const int opair = b / 7;
    const int band  = b % 7;
    const int tid   = threadIdx.x;

    // ---------------- Phase A: stage1 into LDS ----------------
    #pragma unroll
    for (int round = 0; round < 2; ++round) {
        int pair = tid + round * 256;          // (c, pr) task id
        if (pair < 384) {
            int c  = pair / 6;
            int pr = pair % 6;
            int m  = band * 4 + pr - 1;        // input row for padded row
            float* dst = &sA[pair * 36];
            if (m < 0 || m > 27) {
                #pragma unroll
                for (int t = 0; t < 15; ++t)
                    ((float2*)dst)[t] = make_float2(0.f, 0.f);
            } else {
                int j0 = c & ~1;               // input channel pair
                int k  = c & 1;
                const float* xr0 = x + (j0 * 28 + m) * 28;
                const float* xr1 = xr0 + 28 * 28;
                const float* w2p = w2 + j0 * 6 + k;   // w2[j][i][k]
                float wa0 = w2p[0], wa1 = w2p[2],  wa2 = w2p[4];
                float wb0 = w2p[6], wb1 = w2p[8],  wb2 = w2p[10];

                float xp0[30], xp1[30];
                xp0[0] = 0.f; xp0[29] = 0.f;
                xp1[0] = 0.f; xp1[29] = 0.f;
                #pragma unroll
                for (int t = 0; t < 7; ++t) {
                    float4 v0 = ((const float4*)xr0)[t];
                    float4 v1 = ((const float4*)xr1)[t];
                    xp0[1 + 4*t] = v0.x; xp0[2 + 4*t] = v0.y;
                    xp0[3 + 4*t] = v0.z; xp0[4 + 4*t] = v0.w;
                    xp1[1 + 4*t] = v1.x; xp1[2 + 4*t] = v1.y;
                    xp1[3 + 4*t] = v1.z; xp1[4 + 4*t] = v1.w;
                }
                float val[30];
                val[0] = 0.f; val[29] = 0.f;
                #pragma unroll
                for (int px = 1; px <= 28; ++px) {
                    val[px] = wa0 * xp0[px-1] + wa1 * xp0[px] + wa2 * xp0[px+1]
                            + wb0 * xp1[px-1] + wb1 * xp1[px] + wb2 * xp1[px+1];
                }
                #pragma unroll
                for (int t = 0; t < 15; ++t)
                    ((float2*)dst)[t] = make_float2(val[2*t], val[2*t + 1]);
            }
        }
    }
    __syncthreads();

    // ---------------- Phase B: 3x3x64 conv ----------------
    const int oo    = tid >> 7;        // wave-pair uniform
    const int r     = tid & 127;
    const int strip = r >> 2;          // 0..31, active < 28
    const int c4    = r & 3;           // channel split
    const bool act  = (strip < 28);
    const int dh    = strip / 7;       // output row within band
    const int st    = strip % 7;       // 4-col strip
    const int o     = opair * 2 + oo;

    float acc0 = 0.f, acc1 = 0.f, acc2 = 0.f, acc3 = 0.f;
    if (act) {
        const float* wbo = w1 + o * 576;          // w1[o][l][r][s][k]
        #pragma unroll 2
        for (int ci = 0; ci < 16; ++ci) {
            int c = c4 + ci * 4;                  // interleaved for bank spread
            const float* wc = wbo + (c >> 1) * 18 + (c & 1);
            const float* sa = &sA[c * 216 + st * 4];
            #pragma unroll
            for (int dy = 0; dy < 3; ++dy) {
                float w0 = wc[dy*6 + 0];
                float w1v = wc[dy*6 + 2];
                float w2v = wc[dy*6 + 4];
                const float* row = sa + (dh + dy) * 36;
                float4 t0 = *(const float4*)row;
                float2 t1 = *(const float2*)(row + 4);
                acc0 += w0 * t0.x + w1v * t0.y + w2v * t0.z;
                acc1 += w0 * t0.y + w1v * t0.z + w2v * t0.w;
                acc2 += w0 * t0.z + w1v * t0.w + w2v * t1.x;
                acc3 += w0 * t0.w + w1v * t1.x + w2v * t1.y;
            }
        }
    }
    sRed[tid][0] = acc0; sRed[tid][1] = acc1;
    sRed[tid][2] = acc2; sRed[tid][3] = acc3;
    __syncthreads();

    // ---------------- c-split reduction + store ----------------
    if (tid < 224) {
        int oo2 = tid / 112;
        int rr  = tid % 112;
        int dh2 = rr / 28;
        int col = rr % 28;
        int st2 = col >> 2, q = col & 3;
        int base = oo2 * 128 + (dh2 * 7 + st2) * 4;
        float s = sRed[base][q] + sRed[base + 1][q]
                + sRed[base + 2][q] + sRed[base + 3][q];
        int o2 = opair * 2 + oo2;
        int R  = band * 4 + dh2;
        y[(o2 * 28 + R) * 28 + col] = s;
    }
}

extern "C" void kernel_launch(void* const* d_in, const int* in_sizes, int n_in,
                              void* d_out, int out_size, void* d_ws, size_t ws_size,
                              hipStream_t stream) {
    const float* x  = (const float*)d_in[0];   // (1,64,28,28) fp32
    const float* w1 = (const float*)d_in[1];   // (128,32,3,3,2) fp32
    const float* w2 = (const float*)d_in[2];   // (64,3,2) fp32
    float* yout = (float*)d_out;               // (1,128,28,28) fp32

    fused_kernel<<<dim3(448), dim3(256), 0, stream>>>(x, w1, w2, yout);
}